// Round 7
// baseline (259.812 us; speedup 1.0000x reference)
//
#include <hip/hip_runtime.h>
#include <hip/hip_bf16.h>
#include <math.h>

#define B_    2
#define C_    192
#define H_    96
#define W_    96
#define HW_   (H_ * W_)          // 9216
#define NPIX_ (B_ * HW_)         // 18432
#define G_    12
#define CG_   16
#define KPTS_ 9
#define MLPH_ 384
#define OFFCH (G_ * 2 * KPTS_)   // 216

typedef __attribute__((ext_vector_type(8))) short s16x8;
typedef __attribute__((ext_vector_type(4))) float f32x4;

__device__ __forceinline__ ushort f2b(float f) {
    __hip_bfloat16 h = __float2bfloat16(f);
    return *reinterpret_cast<ushort*>(&h);
}
__device__ __forceinline__ float b2f(ushort u) {
    return __uint_as_float(((uint)u) << 16);
}
__device__ __forceinline__ float b2f_lo(uint u) { return __uint_as_float(u << 16); }
__device__ __forceinline__ float b2f_hi(uint u) { return __uint_as_float(u & 0xffff0000u); }

#if __has_builtin(__builtin_amdgcn_fdot2_f32_bf16)
typedef __attribute__((ext_vector_type(2))) __bf16 bf16x2;
#define HAVE_DOT2BF 1
__device__ __forceinline__ float dot2bf(uint a, uint b, float c) {
    return __builtin_amdgcn_fdot2_f32_bf16(__builtin_bit_cast(bf16x2, a),
                                           __builtin_bit_cast(bf16x2, b), c, false);
}
#else
#define HAVE_DOT2BF 0
#endif

#define GLOAD16(gp, lp)                                                          \
    __builtin_amdgcn_global_load_lds(                                            \
        (const __attribute__((address_space(1))) void*)(gp),                     \
        (__attribute__((address_space(3))) void*)(lp), 16, 0, 0)

// chunk swizzle (8-ushort chunks, XOR low-3 of chunk with row&7) — involution
__device__ __forceinline__ int swz(int c, int r) {
    return (c & ~7) | ((c & 7) ^ (r & 7));
}

// ---------------------------------------------------------------------------
// prep (fused): [0,864) pack q/k/v NCHW fp32 -> channels-last bf16 Xcl;
//               [864,1872) wpack weights -> transposed bf16 [N][K]
// ---------------------------------------------------------------------------
__global__ __launch_bounds__(256) void prep_kernel(
    const float* __restrict__ q, const float* __restrict__ k,
    const float* __restrict__ v,
    const float* __restrict__ Wq, const float* __restrict__ Wk,
    const float* __restrict__ Wv, const float* __restrict__ W1,
    const float* __restrict__ W2,
    ushort* __restrict__ Xcl, ushort* __restrict__ Wt)
{
    __shared__ ushort sm[64][196];
    const int bx = blockIdx.x;
    const int t  = threadIdx.x;

    if (bx < 864) {            // ---- pack ----
        const int z   = bx / 288;
        const int rem = bx - z * 288;
        const int b   = rem / 144;
        const int hw0 = (rem - b * 144) * 64;
        const float* X = (z == 0) ? q : (z == 1) ? k : v;

        const int hwl = t & 63;
        #pragma unroll 4
        for (int j = 0; j < 48; ++j) {
            const int c = (t >> 6) + j * 4;
            sm[hwl][c] = f2b(X[(b * C_ + c) * HW_ + hw0 + hwl]);
        }
        __syncthreads();
        #pragma unroll
        for (int jj = 0; jj < 12; ++jj) {
            const int idx = t + 256 * jj;        // < 64*48
            const int row = idx / 48, cq = idx - row * 48;
            const int pix = b * HW_ + hw0 + row;
            *(uint2*)&Xcl[((z * NPIX_) + pix) * C_ + cq * 4] = *(uint2*)&sm[row][cq * 4];
        }
    } else {                   // ---- wpack ----
        const int i = (bx - 864) * 256 + t;
        if (i < 110592) {
            const int s = i / 36864, j = i - s * 36864;
            const float* src = (s == 0) ? Wq : (s == 1) ? Wk : Wv;
            const int d = j / 192, c = j - d * 192;
            Wt[i] = f2b(src[c * 192 + d]);
        } else if (i < 184320) {
            const int j = i - 110592, d = j / 192, c = j - d * 192;
            Wt[i] = f2b(W1[c * 384 + d]);
        } else if (i < 258048) {
            const int j = i - 184320, d = j / 384, c = j - d * 384;
            Wt[i] = f2b(W2[c * 192 + d]);
        }
    }
}

// ---------------------------------------------------------------------------
// proj: single-stage MFMA GEMM, full K=192 staged once, no mid-loop barriers.
//   O = A(128xK) * WT(64xK)^T + bias; z selects q/k/v.
//   z=0 -> qb[pix][192]; z=1/2 -> kvb[pix][g][K16|V16]
// ---------------------------------------------------------------------------
__global__ __launch_bounds__(256) void proj_kernel(
    const ushort* __restrict__ A, const ushort* __restrict__ Wt,
    const float* __restrict__ bq, const float* __restrict__ bk,
    const float* __restrict__ bv,
    ushort* __restrict__ qb, ushort* __restrict__ kvb)
{
    __shared__ char lds[73728];            // A 48KB + B 24KB
    ushort* As = (ushort*)lds;             // [128][24 chunks][8]
    ushort* Bs = (ushort*)lds + 24576;     // [64][24 chunks][8]

    const int t  = threadIdx.x;
    const int l  = t & 63;
    const int wid = t >> 6;
    const int wm = wid >> 1, wn = wid & 1;
    const int m0 = blockIdx.x * 128;
    const int n0 = blockIdx.y * 64;
    const int z  = blockIdx.z;

    const ushort* Az = A  + (size_t)z * NPIX_ * C_;
    const ushort* Bz = Wt + (size_t)z * C_ * C_;
    const float* bias = (z == 0) ? bq : (z == 1) ? bk : bv;

    // stage A (3072 chunks) and B (1536 chunks), linear dest + inv-swz source
    #pragma unroll
    for (int j = 0; j < 12; ++j) {
        const int qq = t + 256 * j;
        const int r = qq / 24, cc = qq - r * 24;
        GLOAD16(Az + (size_t)(m0 + r) * C_ + swz(cc, r) * 8, As + qq * 8);
    }
    #pragma unroll
    for (int j = 0; j < 6; ++j) {
        const int qq = t + 256 * j;
        const int r = qq / 24, cc = qq - r * 24;
        GLOAD16(Bz + (size_t)(n0 + r) * C_ + swz(cc, r) * 8, Bs + qq * 8);
    }
    __syncthreads();

    const int lr = l & 15, lq = l >> 4;
    f32x4 acc[4][2] = {};
    #pragma unroll
    for (int ks = 0; ks < 6; ++ks) {
        const int c = ks * 4 + lq;
        s16x8 af[4], bf[2];
        #pragma unroll
        for (int f = 0; f < 4; ++f) {
            const int r = wm * 64 + f * 16 + lr;
            af[f] = *(const s16x8*)(As + r * 192 + swz(c, r) * 8);
        }
        #pragma unroll
        for (int g = 0; g < 2; ++g) {
            const int r = wn * 32 + g * 16 + lr;
            bf[g] = *(const s16x8*)(Bs + r * 192 + swz(c, r) * 8);
        }
        #pragma unroll
        for (int f = 0; f < 4; ++f)
            #pragma unroll
            for (int g = 0; g < 2; ++g)
                acc[f][g] = __builtin_amdgcn_mfma_f32_16x16x32_bf16(af[f], bf[g], acc[f][g], 0, 0, 0);
    }

    float bvv[2];
    #pragma unroll
    for (int g = 0; g < 2; ++g) bvv[g] = bias[n0 + wn * 32 + g * 16 + lr];

    if (z == 0) {
        #pragma unroll
        for (int f = 0; f < 4; ++f)
            #pragma unroll
            for (int g = 0; g < 2; ++g)
                #pragma unroll
                for (int r = 0; r < 4; ++r) {
                    const int m = m0 + wm * 64 + f * 16 + lq * 4 + r;
                    const int n = n0 + wn * 32 + g * 16 + lr;
                    qb[(size_t)m * C_ + n] = f2b(acc[f][g][r] + bvv[g]);
                }
    } else {
        const int voff = (z == 2) ? 16 : 0;
        #pragma unroll
        for (int f = 0; f < 4; ++f)
            #pragma unroll
            for (int g = 0; g < 2; ++g) {
                const int grp = (n0 >> 4) + wn * 2 + g;
                #pragma unroll
                for (int r = 0; r < 4; ++r) {
                    const int m = m0 + wm * 64 + f * 16 + lq * 4 + r;
                    kvb[(size_t)m * (2 * C_) + grp * 32 + voff + lr] =
                        f2b(acc[f][g][r] + bvv[g]);
                }
            }
    }
}

// ---------------------------------------------------------------------------
// deformable attention v6: 4 lanes per (pixel, group); lane owns 4 channels.
// kv block-interleaved [pix][g][K16|V16]; addr/wgt precomputed branch-free;
// V RE-GATHERED after softmax (same 64B line, L1/L2-hot) -> no spill.
// ---------------------------------------------------------------------------
__global__ __launch_bounds__(256, 4) void deform_attn_kernel(
    const ushort* __restrict__ qb, const ushort* __restrict__ kvb,
    const float* __restrict__ offset, ushort* __restrict__ aob)
{
    const int t   = threadIdx.x;
    const int bid = blockIdx.x;                    // 3456 blocks
    const int xb  = (bid & 7) * 432 + (bid >> 3);  // XCD-chunked swizzle
    const int pair = xb * 64 + (t >> 2);
    const int lane4 = t & 3;
    const int g   = pair % G_;
    const int pix = pair / G_;
    const int b   = pix / HW_;
    const int hw  = pix - b * HW_;
    const int h   = hw / W_;
    const int w   = hw - h * W_;
    const int gc0 = g * CG_ + lane4 * 4;

    // q: 4 channels
    uint2 qu = *(const uint2*)(qb + (size_t)pix * C_ + gc0);

    // offsets: lane l holds points l, l+4, l+8
    float offy[3] = {0.f, 0.f, 0.f}, offx[3] = {0.f, 0.f, 0.f};
    {
        const int obase = (b * OFFCH + g * (2 * KPTS_)) * HW_ + hw;
        #pragma unroll
        for (int s = 0; s < 3; ++s) {
            const int kk = lane4 + s * 4;
            if (kk < KPTS_) {
                offy[s] = offset[obase + (kk * 2) * HW_];
                offx[s] = offset[obase + (kk * 2 + 1) * HW_];
            }
        }
    }

    // all 36 corner addresses + masked weights, branch-free
    int   addr[KPTS_][4];
    float wgt[KPTS_][4];
    #pragma unroll
    for (int kk = 0; kk < KPTS_; ++kk) {
        const float oy = __shfl(offy[kk >> 2], kk & 3, 4);
        const float ox = __shfl(offx[kk >> 2], kk & 3, 4);
        const float py = (float)(h - 1 + kk / 3) + oy;
        const float px = (float)(w - 1 + kk % 3) + ox;
        const float fy = floorf(py), fx = floorf(px);
        const int   y0 = (int)fy,   x0 = (int)fx;
        const float wy1 = py - fy, wx1 = px - fx;
        const float wy0 = 1.f - wy1, wx0 = 1.f - wx1;

        const float wy0m = ((unsigned)y0       < (unsigned)H_) ? wy0 : 0.f;
        const float wy1m = ((unsigned)(y0 + 1) < (unsigned)H_) ? wy1 : 0.f;
        const float wx0m = ((unsigned)x0       < (unsigned)W_) ? wx0 : 0.f;
        const float wx1m = ((unsigned)(x0 + 1) < (unsigned)W_) ? wx1 : 0.f;
        const int yc0 = min(max(y0, 0), H_ - 1);
        const int yc1 = min(max(y0 + 1, 0), H_ - 1);
        const int xc0 = min(max(x0, 0), W_ - 1);
        const int xc1 = min(max(x0 + 1, 0), W_ - 1);

        const int kvbase = g * 32 + lane4 * 4;
        addr[kk][0] = ((b * HW_ + yc0 * W_ + xc0) * (2 * C_)) + kvbase;  wgt[kk][0] = wy0m * wx0m;
        addr[kk][1] = ((b * HW_ + yc0 * W_ + xc1) * (2 * C_)) + kvbase;  wgt[kk][1] = wy0m * wx1m;
        addr[kk][2] = ((b * HW_ + yc1 * W_ + xc0) * (2 * C_)) + kvbase;  wgt[kk][2] = wy1m * wx0m;
        addr[kk][3] = ((b * HW_ + yc1 * W_ + xc1) * (2 * C_)) + kvbase;  wgt[kk][3] = wy1m * wx1m;
    }

    // ---- K-pass ----
    float score[KPTS_];
    #pragma unroll
    for (int kk = 0; kk < KPTS_; ++kk) {
        float s = 0.f;
        #pragma unroll
        for (int c = 0; c < 4; ++c) {
            const uint2 ku = *(const uint2*)(kvb + addr[kk][c]);
#if HAVE_DOT2BF
            const float d = dot2bf(ku.y, qu.y, dot2bf(ku.x, qu.x, 0.f));
#else
            float d = b2f_lo(qu.x) * b2f_lo(ku.x);
            d = fmaf(b2f_hi(qu.x), b2f_hi(ku.x), d);
            d = fmaf(b2f_lo(qu.y), b2f_lo(ku.y), d);
            d = fmaf(b2f_hi(qu.y), b2f_hi(ku.y), d);
#endif
            s = fmaf(wgt[kk][c], d, s);
        }
        score[kk] = s;
    }
    #pragma unroll
    for (int kk = 0; kk < KPTS_; ++kk) {
        float sc = score[kk];
        sc += __shfl_xor(sc, 1, 4);
        sc += __shfl_xor(sc, 2, 4);
        score[kk] = sc * 0.25f;   // hd^-0.5
    }

    // softmax over 9 points
    float m = score[0];
    #pragma unroll
    for (int kk = 1; kk < KPTS_; ++kk) m = fmaxf(m, score[kk]);
    float ssum = 0.f;
    #pragma unroll
    for (int kk = 0; kk < KPTS_; ++kk) { score[kk] = __expf(score[kk] - m); ssum += score[kk]; }
    const float inv = 1.f / ssum;

    // ---- V-pass: re-gather (L1/L2-hot lines) ----
    f32x4 o = {0.f, 0.f, 0.f, 0.f};
    #pragma unroll
    for (int kk = 0; kk < KPTS_; ++kk) {
        const float p = score[kk];
        #pragma unroll
        for (int c = 0; c < 4; ++c) {
            const float pw = p * wgt[kk][c];
            const uint2 vv = *(const uint2*)(kvb + addr[kk][c] + 16);
            o[0] = fmaf(pw, b2f_lo(vv.x), o[0]);
            o[1] = fmaf(pw, b2f_hi(vv.x), o[1]);
            o[2] = fmaf(pw, b2f_lo(vv.y), o[2]);
            o[3] = fmaf(pw, b2f_hi(vv.y), o[3]);
        }
    }

    uint2 obv;
    obv.x = (uint)f2b(o[0] * inv) | ((uint)f2b(o[1] * inv) << 16);
    obv.y = (uint)f2b(o[2] * inv) | ((uint)f2b(o[3] * inv) << 16);
    *(uint2*)(aob + (size_t)pix * C_ + gc0) = obv;
}

// ---------------------------------------------------------------------------
// fused MLP: per 64-pixel block, A (24KB) + H (48KB) in LDS; H never in HBM.
//   H = gelu(A @ W1 + b1); out = A + H @ W2 + b2, NCHW fp32.
// 4 waves: phase1 each wave owns 96 cols of H; phase2 48 cols of out.
// ---------------------------------------------------------------------------
__global__ __launch_bounds__(256) void mlp_fused_kernel(
    const ushort* __restrict__ aob, const ushort* __restrict__ W1T,
    const ushort* __restrict__ W2T, const float* __restrict__ b1,
    const float* __restrict__ b2, float* __restrict__ out)
{
    __shared__ char lds[73728];
    ushort* As = (ushort*)lds;             // [64][24 chunks][8] swizzled
    ushort* Hs = (ushort*)lds + 12288;     // [64][48 chunks][8] swizzled

    const int t = threadIdx.x;
    const int l = t & 63;
    const int w = t >> 6;
    const int pix0 = blockIdx.x * 64;
    const int lr = l & 15, lq = l >> 4;

    // stage A tile
    #pragma unroll
    for (int j = 0; j < 6; ++j) {
        const int qq = t + 256 * j;
        const int r = qq / 24, cc = qq - r * 24;
        GLOAD16(aob + (size_t)(pix0 + r) * C_ + swz(cc, r) * 8, As + qq * 8);
    }
    __syncthreads();

    // ---- phase 1: H = gelu(A @ W1 + b1), wave covers 96 cols ----
    const int n0w = w * 96;
    f32x4 acc1[4][6] = {};
    #pragma unroll
    for (int ks = 0; ks < 6; ++ks) {
        const int c = ks * 4 + lq;
        s16x8 af[4], bf[6];
        #pragma unroll
        for (int f = 0; f < 4; ++f) {
            const int r = f * 16 + lr;
            af[f] = *(const s16x8*)(As + r * 192 + swz(c, r) * 8);
        }
        #pragma unroll
        for (int g = 0; g < 6; ++g)
            bf[g] = *(const s16x8*)(W1T + (size_t)(n0w + g * 16 + lr) * C_ + ks * 32 + lq * 8);
        #pragma unroll
        for (int f = 0; f < 4; ++f)
            #pragma unroll
            for (int g = 0; g < 6; ++g)
                acc1[f][g] = __builtin_amdgcn_mfma_f32_16x16x32_bf16(af[f], bf[g], acc1[f][g], 0, 0, 0);
    }
    #pragma unroll
    for (int g = 0; g < 6; ++g) {
        const int n = n0w + g * 16 + lr;
        const float bb = b1[n];
        const int c = n >> 3, nlo = n & 7;
        #pragma unroll
        for (int f = 0; f < 4; ++f)
            #pragma unroll
            for (int r = 0; r < 4; ++r) {
                const int m = f * 16 + lq * 4 + r;
                const float x = acc1[f][g][r] + bb;
                Hs[m * 384 + swz(c, m) * 8 + nlo] =
                    f2b(0.5f * x * (1.f + erff(x * 0.70710678118f)));
            }
    }
    __syncthreads();

    // ---- phase 2: out = A + H @ W2 + b2, wave covers 48 cols ----
    const int n0w2 = w * 48;
    f32x4 acc2[4][3] = {};
    #pragma unroll
    for (int ks = 0; ks < 12; ++ks) {
        const int c = ks * 4 + lq;
        s16x8 af[4], bf[3];
        #pragma unroll
        for (int f = 0; f < 4; ++f) {
            const int r = f * 16 + lr;
            af[f] = *(const s16x8*)(Hs + r * 384 + swz(c, r) * 8);
        }
        #pragma unroll
        for (int g = 0; g < 3; ++g)
            bf[g] = *(const s16x8*)(W2T + (size_t)(n0w2 + g * 16 + lr) * MLPH_ + ks * 32 + lq * 8);
        #pragma unroll
        for (int f = 0; f < 4; ++f)
            #pragma unroll
            for (int g = 0; g < 3; ++g)
                acc2[f][g] = __builtin_amdgcn_mfma_f32_16x16x32_bf16(af[f], bf[g], acc2[f][g], 0, 0, 0);
    }
    // bias + residual (read As before it is clobbered by tsp)
    #pragma unroll
    for (int g = 0; g < 3; ++g) {
        const int n = n0w2 + g * 16 + lr;
        const float bb = b2[n];
        const int c = n >> 3, nlo = n & 7;
        #pragma unroll
        for (int f = 0; f < 4; ++f)
            #pragma unroll
            for (int r = 0; r < 4; ++r) {
                const int m = f * 16 + lq * 4 + r;
                acc2[f][g][r] += bb + b2f(As[m * 192 + swz(c, m) * 8 + nlo]);
            }
    }
    __syncthreads();
    float* tsp = (float*)lds;   // [192][68]
    #pragma unroll
    for (int g = 0; g < 3; ++g) {
        const int n = n0w2 + g * 16 + lr;
        #pragma unroll
        for (int f = 0; f < 4; ++f)
            #pragma unroll
            for (int r = 0; r < 4; ++r) {
                const int m = f * 16 + lq * 4 + r;
                tsp[n * 68 + m] = acc2[f][g][r];
            }
    }
    __syncthreads();
    const int b   = pix0 / HW_;
    const int hw0 = pix0 - b * HW_;
    #pragma unroll
    for (int j = 0; j < 12; ++j) {
        const int i = t + 256 * j;          // < 192*16
        const int nn = i >> 4, mc = i & 15;
        float4 val = *(float4*)&tsp[nn * 68 + mc * 4];
        *(float4*)&out[(size_t)(b * C_ + nn) * HW_ + hw0 + mc * 4] = val;
    }
}

// ---------------------------------------------------------------------------
extern "C" void kernel_launch(void* const* d_in, const int* in_sizes, int n_in,
                              void* d_out, int out_size, void* d_ws, size_t ws_size,
                              hipStream_t stream)
{
    const float* q      = (const float*)d_in[0];
    const float* k      = (const float*)d_in[1];
    const float* v      = (const float*)d_in[2];
    const float* offset = (const float*)d_in[3];
    const float* Wq     = (const float*)d_in[4];
    const float* bq     = (const float*)d_in[5];
    const float* Wk     = (const float*)d_in[6];
    const float* bk     = (const float*)d_in[7];
    const float* Wv     = (const float*)d_in[8];
    const float* bv     = (const float*)d_in[9];
    const float* W1     = (const float*)d_in[10];
    const float* b1     = (const float*)d_in[11];
    const float* W2     = (const float*)d_in[12];
    const float* b2     = (const float*)d_in[13];

    ushort* Xcl = (ushort*)d_ws;                    // [3][NPIX][192] bf16
    ushort* aob = Xcl;                              // alias: Xcl dead after proj
    ushort* qb  = Xcl + (size_t)3 * NPIX_ * C_;     // [NPIX][192] bf16
    ushort* kvb = qb  + (size_t)NPIX_ * C_;         // [NPIX][12][K16|V16] bf16
    ushort* Wt  = kvb + (size_t)NPIX_ * 2 * C_;     // transposed bf16 weights
    ushort* W1T = Wt + 110592;
    ushort* W2T = Wt + 184320;

    prep_kernel<<<1872, 256, 0, stream>>>(q, k, v, Wq, Wk, Wv, W1, W2, Xcl, Wt);

    proj_kernel<<<dim3(NPIX_ / 128, 3, 3), 256, 0, stream>>>(
        Xcl, Wt, bq, bk, bv, qb, kvb);

    deform_attn_kernel<<<NPIX_ * G_ / 64, 256, 0, stream>>>(qb, kvb, offset, aob);

    mlp_fused_kernel<<<NPIX_ / 64, 256, 0, stream>>>(
        aob, W1T, W2T, b1, b2, (float*)d_out);
}

// Round 8
// 210.635 us; speedup vs baseline: 1.2335x; 1.2335x over previous
//
#include <hip/hip_runtime.h>
#include <hip/hip_bf16.h>
#include <math.h>

#define B_    2
#define C_    192
#define H_    96
#define W_    96
#define HW_   (H_ * W_)          // 9216
#define NPIX_ (B_ * HW_)         // 18432
#define G_    12
#define CG_   16
#define KPTS_ 9
#define MLPH_ 384
#define OFFCH (G_ * 2 * KPTS_)   // 216

typedef __attribute__((ext_vector_type(8))) short s16x8;
typedef __attribute__((ext_vector_type(4))) float f32x4;

__device__ __forceinline__ ushort f2b(float f) {
    __hip_bfloat16 h = __float2bfloat16(f);
    return *reinterpret_cast<ushort*>(&h);
}
__device__ __forceinline__ float b2f(ushort u) {
    return __uint_as_float(((uint)u) << 16);
}
__device__ __forceinline__ float b2f_lo(uint u) { return __uint_as_float(u << 16); }
__device__ __forceinline__ float b2f_hi(uint u) { return __uint_as_float(u & 0xffff0000u); }

#if __has_builtin(__builtin_amdgcn_fdot2_f32_bf16)
typedef __attribute__((ext_vector_type(2))) __bf16 bf16x2;
#define HAVE_DOT2BF 1
__device__ __forceinline__ float dot2bf(uint a, uint b, float c) {
    return __builtin_amdgcn_fdot2_f32_bf16(__builtin_bit_cast(bf16x2, a),
                                           __builtin_bit_cast(bf16x2, b), c, false);
}
#else
#define HAVE_DOT2BF 0
#endif

#define GLOAD16(gp, lp)                                                          \
    __builtin_amdgcn_global_load_lds(                                            \
        (const __attribute__((address_space(1))) void*)(gp),                     \
        (__attribute__((address_space(3))) void*)(lp), 16, 0, 0)

// chunk swizzle (8-ushort chunks, XOR low-3 of chunk with row&7) — involution
__device__ __forceinline__ int swz(int c, int r) {
    return (c & ~7) | ((c & 7) ^ (r & 7));
}

// ---------------------------------------------------------------------------
// prep: wpack weights fp32 -> TRANSPOSED bf16 [N][K] (1008 blocks)
// ---------------------------------------------------------------------------
__global__ __launch_bounds__(256) void prep_kernel(
    const float* __restrict__ Wq, const float* __restrict__ Wk,
    const float* __restrict__ Wv, const float* __restrict__ W1,
    const float* __restrict__ W2, ushort* __restrict__ Wt)
{
    const int i = blockIdx.x * 256 + threadIdx.x;
    if (i < 110592) {
        const int s = i / 36864, j = i - s * 36864;
        const float* src = (s == 0) ? Wq : (s == 1) ? Wk : Wv;
        const int d = j / 192, c = j - d * 192;
        Wt[i] = f2b(src[c * 192 + d]);
    } else if (i < 184320) {
        const int j = i - 110592, d = j / 192, c = j - d * 192;
        Wt[i] = f2b(W1[c * 384 + d]);
    } else if (i < 258048) {
        const int j = i - 184320, d = j / 384, c = j - d * 384;
        Wt[i] = f2b(W2[c * 192 + d]);
    }
}

// ---------------------------------------------------------------------------
// proj: single-stage MFMA GEMM reading fp32 NCHW directly (pack fused in).
//   A-tile: 128 pixels x 192 ch, reg-staged fp32->bf16 into swizzled LDS.
//   B-tile: Wt[N][K] bf16 via global_load_lds.
//   Grid: 1296 blocks, XCD-bijective swizzle; decode (z, m0, n0) with the
//   3 n-tiles of an m-tile consecutive (A-tile L2 reuse on one XCD).
//   z=0 -> qb[pix][192]; z=1/2 -> kvb[pix][g][K16|V16]
// ---------------------------------------------------------------------------
__global__ __launch_bounds__(256) void proj_kernel(
    const float* __restrict__ q, const float* __restrict__ k,
    const float* __restrict__ v, const ushort* __restrict__ Wt,
    const float* __restrict__ bq, const float* __restrict__ bk,
    const float* __restrict__ bv,
    ushort* __restrict__ qb, ushort* __restrict__ kvb)
{
    __shared__ char lds[73728];            // A 48KB + B 24KB
    ushort* As = (ushort*)lds;             // [128][24 chunks][8] swizzled
    ushort* Bs = (ushort*)lds + 24576;     // [64][24 chunks][8] swizzled

    const int t   = threadIdx.x;
    const int bid = blockIdx.x;                    // 1296 = 8 * 162
    const int lg  = (bid & 7) * 162 + (bid >> 3);  // XCD-chunked, bijective
    const int z   = lg / 432;
    const int rem = lg - z * 432;
    const int mt  = rem / 3;
    const int m0  = mt * 128;
    const int n0  = (rem - mt * 3) * 64;

    const float* X = (z == 0) ? q : (z == 1) ? k : v;
    const float* bias = (z == 0) ? bq : (z == 1) ? bk : bv;
    const int b   = m0 / HW_;
    const int hw0 = m0 - b * HW_;

    // B staging (1536 chunks) via global_load_lds
    const ushort* Bz = Wt + (size_t)z * C_ * C_;
    #pragma unroll
    for (int j = 0; j < 6; ++j) {
        const int qq = t + 256 * j;
        const int r = qq / 24, cc = qq - r * 24;
        GLOAD16(Bz + (size_t)(n0 + r) * C_ + swz(cc, r) * 8, Bs + qq * 8);
    }

    // A staging: reg-stage fp32 NCHW, convert, swizzled b128 writes.
    // lane tt = pixel, ch2 selects even/odd chunk; 8 coalesced dword loads/chunk.
    {
        const int r   = t & 127;
        const int ch2 = t >> 7;
        const float* Xb = X + (size_t)b * C_ * HW_ + hw0 + r;
        #pragma unroll
        for (int j = 0; j < 12; ++j) {
            const int cg8 = j * 2 + ch2;     // chunk 0..23
            const float* Xc = Xb + (size_t)(cg8 * 8) * HW_;
            s16x8 val;
            #pragma unroll
            for (int e = 0; e < 8; ++e)
                val[e] = (short)f2b(Xc[(size_t)e * HW_]);
            *(s16x8*)(As + r * 192 + swz(cg8, r) * 8) = val;
        }
    }
    __syncthreads();

    const int l  = t & 63;
    const int wid = t >> 6;
    const int wm = wid >> 1, wn = wid & 1;
    const int lr = l & 15, lq = l >> 4;

    f32x4 acc[4][2] = {};
    #pragma unroll
    for (int ks = 0; ks < 6; ++ks) {
        const int c = ks * 4 + lq;
        s16x8 af[4], bf[2];
        #pragma unroll
        for (int f = 0; f < 4; ++f) {
            const int r = wm * 64 + f * 16 + lr;
            af[f] = *(const s16x8*)(As + r * 192 + swz(c, r) * 8);
        }
        #pragma unroll
        for (int g = 0; g < 2; ++g) {
            const int r = wn * 32 + g * 16 + lr;
            bf[g] = *(const s16x8*)(Bs + r * 192 + swz(c, r) * 8);
        }
        #pragma unroll
        for (int f = 0; f < 4; ++f)
            #pragma unroll
            for (int g = 0; g < 2; ++g)
                acc[f][g] = __builtin_amdgcn_mfma_f32_16x16x32_bf16(af[f], bf[g], acc[f][g], 0, 0, 0);
    }

    float bvv[2];
    #pragma unroll
    for (int g = 0; g < 2; ++g) bvv[g] = bias[n0 + wn * 32 + g * 16 + lr];

    if (z == 0) {
        #pragma unroll
        for (int f = 0; f < 4; ++f)
            #pragma unroll
            for (int g = 0; g < 2; ++g)
                #pragma unroll
                for (int r = 0; r < 4; ++r) {
                    const int m = m0 + wm * 64 + f * 16 + lq * 4 + r;
                    const int n = n0 + wn * 32 + g * 16 + lr;
                    qb[(size_t)m * C_ + n] = f2b(acc[f][g][r] + bvv[g]);
                }
    } else {
        const int voff = (z == 2) ? 16 : 0;
        #pragma unroll
        for (int f = 0; f < 4; ++f)
            #pragma unroll
            for (int g = 0; g < 2; ++g) {
                const int grp = (n0 >> 4) + wn * 2 + g;
                #pragma unroll
                for (int r = 0; r < 4; ++r) {
                    const int m = m0 + wm * 64 + f * 16 + lq * 4 + r;
                    kvb[(size_t)m * (2 * C_) + grp * 32 + voff + lr] =
                        f2b(acc[f][g][r] + bvv[g]);
                }
            }
    }
}

// ---------------------------------------------------------------------------
// deformable attention v6: 4 lanes per (pixel, group); lane owns 4 channels.
// kv block-interleaved [pix][g][K16|V16]; addr/wgt precomputed branch-free;
// V re-gathered after softmax (same 64B line, L1/L2-hot).
// launch_bounds (256,2): VGPR cap 128 — NO spill (R7 lesson: (256,4) -> 64 VGPR
// -> 117MB scratch writes, 2.3x slower).
// ---------------------------------------------------------------------------
__global__ __launch_bounds__(256, 2) void deform_attn_kernel(
    const ushort* __restrict__ qb, const ushort* __restrict__ kvb,
    const float* __restrict__ offset, ushort* __restrict__ aob)
{
    const int t   = threadIdx.x;
    const int bid = blockIdx.x;                    // 3456 blocks
    const int xb  = (bid & 7) * 432 + (bid >> 3);  // XCD-chunked swizzle
    const int pair = xb * 64 + (t >> 2);
    const int lane4 = t & 3;
    const int g   = pair % G_;
    const int pix = pair / G_;
    const int b   = pix / HW_;
    const int hw  = pix - b * HW_;
    const int h   = hw / W_;
    const int w   = hw - h * W_;
    const int gc0 = g * CG_ + lane4 * 4;

    // q: 4 channels
    uint2 qu = *(const uint2*)(qb + (size_t)pix * C_ + gc0);

    // offsets: lane l holds points l, l+4, l+8
    float offy[3] = {0.f, 0.f, 0.f}, offx[3] = {0.f, 0.f, 0.f};
    {
        const int obase = (b * OFFCH + g * (2 * KPTS_)) * HW_ + hw;
        #pragma unroll
        for (int s = 0; s < 3; ++s) {
            const int kk = lane4 + s * 4;
            if (kk < KPTS_) {
                offy[s] = offset[obase + (kk * 2) * HW_];
                offx[s] = offset[obase + (kk * 2 + 1) * HW_];
            }
        }
    }

    // all 36 corner addresses + masked weights, branch-free
    int   addr[KPTS_][4];
    float wgt[KPTS_][4];
    #pragma unroll
    for (int kk = 0; kk < KPTS_; ++kk) {
        const float oy = __shfl(offy[kk >> 2], kk & 3, 4);
        const float ox = __shfl(offx[kk >> 2], kk & 3, 4);
        const float py = (float)(h - 1 + kk / 3) + oy;
        const float px = (float)(w - 1 + kk % 3) + ox;
        const float fy = floorf(py), fx = floorf(px);
        const int   y0 = (int)fy,   x0 = (int)fx;
        const float wy1 = py - fy, wx1 = px - fx;
        const float wy0 = 1.f - wy1, wx0 = 1.f - wx1;

        const float wy0m = ((unsigned)y0       < (unsigned)H_) ? wy0 : 0.f;
        const float wy1m = ((unsigned)(y0 + 1) < (unsigned)H_) ? wy1 : 0.f;
        const float wx0m = ((unsigned)x0       < (unsigned)W_) ? wx0 : 0.f;
        const float wx1m = ((unsigned)(x0 + 1) < (unsigned)W_) ? wx1 : 0.f;
        const int yc0 = min(max(y0, 0), H_ - 1);
        const int yc1 = min(max(y0 + 1, 0), H_ - 1);
        const int xc0 = min(max(x0, 0), W_ - 1);
        const int xc1 = min(max(x0 + 1, 0), W_ - 1);

        const int kvbase = g * 32 + lane4 * 4;
        addr[kk][0] = ((b * HW_ + yc0 * W_ + xc0) * (2 * C_)) + kvbase;  wgt[kk][0] = wy0m * wx0m;
        addr[kk][1] = ((b * HW_ + yc0 * W_ + xc1) * (2 * C_)) + kvbase;  wgt[kk][1] = wy0m * wx1m;
        addr[kk][2] = ((b * HW_ + yc1 * W_ + xc0) * (2 * C_)) + kvbase;  wgt[kk][2] = wy1m * wx0m;
        addr[kk][3] = ((b * HW_ + yc1 * W_ + xc1) * (2 * C_)) + kvbase;  wgt[kk][3] = wy1m * wx1m;
    }

    // ---- K-pass ----
    float score[KPTS_];
    #pragma unroll
    for (int kk = 0; kk < KPTS_; ++kk) {
        float s = 0.f;
        #pragma unroll
        for (int c = 0; c < 4; ++c) {
            const uint2 ku = *(const uint2*)(kvb + addr[kk][c]);
#if HAVE_DOT2BF
            const float d = dot2bf(ku.y, qu.y, dot2bf(ku.x, qu.x, 0.f));
#else
            float d = b2f_lo(qu.x) * b2f_lo(ku.x);
            d = fmaf(b2f_hi(qu.x), b2f_hi(ku.x), d);
            d = fmaf(b2f_lo(qu.y), b2f_lo(ku.y), d);
            d = fmaf(b2f_hi(qu.y), b2f_hi(ku.y), d);
#endif
            s = fmaf(wgt[kk][c], d, s);
        }
        score[kk] = s;
    }
    #pragma unroll
    for (int kk = 0; kk < KPTS_; ++kk) {
        float sc = score[kk];
        sc += __shfl_xor(sc, 1, 4);
        sc += __shfl_xor(sc, 2, 4);
        score[kk] = sc * 0.25f;   // hd^-0.5
    }

    // softmax over 9 points
    float m = score[0];
    #pragma unroll
    for (int kk = 1; kk < KPTS_; ++kk) m = fmaxf(m, score[kk]);
    float ssum = 0.f;
    #pragma unroll
    for (int kk = 0; kk < KPTS_; ++kk) { score[kk] = __expf(score[kk] - m); ssum += score[kk]; }
    const float inv = 1.f / ssum;

    // ---- V-pass: re-gather (L1/L2-hot lines) ----
    f32x4 o = {0.f, 0.f, 0.f, 0.f};
    #pragma unroll
    for (int kk = 0; kk < KPTS_; ++kk) {
        const float p = score[kk];
        #pragma unroll
        for (int c = 0; c < 4; ++c) {
            const float pw = p * wgt[kk][c];
            const uint2 vv = *(const uint2*)(kvb + addr[kk][c] + 16);
            o[0] = fmaf(pw, b2f_lo(vv.x), o[0]);
            o[1] = fmaf(pw, b2f_hi(vv.x), o[1]);
            o[2] = fmaf(pw, b2f_lo(vv.y), o[2]);
            o[3] = fmaf(pw, b2f_hi(vv.y), o[3]);
        }
    }

    uint2 obv;
    obv.x = (uint)f2b(o[0] * inv) | ((uint)f2b(o[1] * inv) << 16);
    obv.y = (uint)f2b(o[2] * inv) | ((uint)f2b(o[3] * inv) << 16);
    *(uint2*)(aob + (size_t)pix * C_ + gc0) = obv;
}

// ---------------------------------------------------------------------------
// fused MLP: per 64-pixel block, A (24KB) + H (48KB) in LDS; H never in HBM.
//   H = gelu(A @ W1 + b1); out = A + H @ W2 + b2, NCHW fp32.
// ---------------------------------------------------------------------------
__global__ __launch_bounds__(256) void mlp_fused_kernel(
    const ushort* __restrict__ aob, const ushort* __restrict__ W1T,
    const ushort* __restrict__ W2T, const float* __restrict__ b1,
    const float* __restrict__ b2, float* __restrict__ out)
{
    __shared__ char lds[73728];
    ushort* As = (ushort*)lds;             // [64][24 chunks][8] swizzled
    ushort* Hs = (ushort*)lds + 12288;     // [64][48 chunks][8] swizzled

    const int t = threadIdx.x;
    const int l = t & 63;
    const int w = t >> 6;
    const int pix0 = blockIdx.x * 64;
    const int lr = l & 15, lq = l >> 4;

    // stage A tile
    #pragma unroll
    for (int j = 0; j < 6; ++j) {
        const int qq = t + 256 * j;
        const int r = qq / 24, cc = qq - r * 24;
        GLOAD16(aob + (size_t)(pix0 + r) * C_ + swz(cc, r) * 8, As + qq * 8);
    }
    __syncthreads();

    // ---- phase 1: H = gelu(A @ W1 + b1), wave covers 96 cols ----
    const int n0w = w * 96;
    f32x4 acc1[4][6] = {};
    #pragma unroll
    for (int ks = 0; ks < 6; ++ks) {
        const int c = ks * 4 + lq;
        s16x8 af[4], bf[6];
        #pragma unroll
        for (int f = 0; f < 4; ++f) {
            const int r = f * 16 + lr;
            af[f] = *(const s16x8*)(As + r * 192 + swz(c, r) * 8);
        }
        #pragma unroll
        for (int g = 0; g < 6; ++g)
            bf[g] = *(const s16x8*)(W1T + (size_t)(n0w + g * 16 + lr) * C_ + ks * 32 + lq * 8);
        #pragma unroll
        for (int f = 0; f < 4; ++f)
            #pragma unroll
            for (int g = 0; g < 6; ++g)
                acc1[f][g] = __builtin_amdgcn_mfma_f32_16x16x32_bf16(af[f], bf[g], acc1[f][g], 0, 0, 0);
    }
    #pragma unroll
    for (int g = 0; g < 6; ++g) {
        const int n = n0w + g * 16 + lr;
        const float bb = b1[n];
        const int c = n >> 3, nlo = n & 7;
        #pragma unroll
        for (int f = 0; f < 4; ++f)
            #pragma unroll
            for (int r = 0; r < 4; ++r) {
                const int m = f * 16 + lq * 4 + r;
                const float x = acc1[f][g][r] + bb;
                Hs[m * 384 + swz(c, m) * 8 + nlo] =
                    f2b(0.5f * x * (1.f + erff(x * 0.70710678118f)));
            }
    }
    __syncthreads();

    // ---- phase 2: out = A + H @ W2 + b2, wave covers 48 cols ----
    const int n0w2 = w * 48;
    f32x4 acc2[4][3] = {};
    #pragma unroll
    for (int ks = 0; ks < 12; ++ks) {
        const int c = ks * 4 + lq;
        s16x8 af[4], bf[3];
        #pragma unroll
        for (int f = 0; f < 4; ++f) {
            const int r = f * 16 + lr;
            af[f] = *(const s16x8*)(Hs + r * 384 + swz(c, r) * 8);
        }
        #pragma unroll
        for (int g = 0; g < 3; ++g)
            bf[g] = *(const s16x8*)(W2T + (size_t)(n0w2 + g * 16 + lr) * MLPH_ + ks * 32 + lq * 8);
        #pragma unroll
        for (int f = 0; f < 4; ++f)
            #pragma unroll
            for (int g = 0; g < 3; ++g)
                acc2[f][g] = __builtin_amdgcn_mfma_f32_16x16x32_bf16(af[f], bf[g], acc2[f][g], 0, 0, 0);
    }
    // bias + residual (read As before it is clobbered by tsp)
    #pragma unroll
    for (int g = 0; g < 3; ++g) {
        const int n = n0w2 + g * 16 + lr;
        const float bb = b2[n];
        const int c = n >> 3, nlo = n & 7;
        #pragma unroll
        for (int f = 0; f < 4; ++f)
            #pragma unroll
            for (int r = 0; r < 4; ++r) {
                const int m = f * 16 + lq * 4 + r;
                acc2[f][g][r] += bb + b2f(As[m * 192 + swz(c, m) * 8 + nlo]);
            }
    }
    __syncthreads();
    float* tsp = (float*)lds;   // [192][68]
    #pragma unroll
    for (int g = 0; g < 3; ++g) {
        const int n = n0w2 + g * 16 + lr;
        #pragma unroll
        for (int f = 0; f < 4; ++f)
            #pragma unroll
            for (int r = 0; r < 4; ++r) {
                const int m = f * 16 + lq * 4 + r;
                tsp[n * 68 + m] = acc2[f][g][r];
            }
    }
    __syncthreads();
    const int b   = pix0 / HW_;
    const int hw0 = pix0 - b * HW_;
    #pragma unroll
    for (int j = 0; j < 12; ++j) {
        const int i = t + 256 * j;          // < 192*16
        const int nn = i >> 4, mc = i & 15;
        float4 val = *(float4*)&tsp[nn * 68 + mc * 4];
        *(float4*)&out[(size_t)(b * C_ + nn) * HW_ + hw0 + mc * 4] = val;
    }
}

// ---------------------------------------------------------------------------
extern "C" void kernel_launch(void* const* d_in, const int* in_sizes, int n_in,
                              void* d_out, int out_size, void* d_ws, size_t ws_size,
                              hipStream_t stream)
{
    const float* q      = (const float*)d_in[0];
    const float* k      = (const float*)d_in[1];
    const float* v      = (const float*)d_in[2];
    const float* offset = (const float*)d_in[3];
    const float* Wq     = (const float*)d_in[4];
    const float* bq     = (const float*)d_in[5];
    const float* Wk     = (const float*)d_in[6];
    const float* bk     = (const float*)d_in[7];
    const float* Wv     = (const float*)d_in[8];
    const float* bv     = (const float*)d_in[9];
    const float* W1     = (const float*)d_in[10];
    const float* b1     = (const float*)d_in[11];
    const float* W2     = (const float*)d_in[12];
    const float* b2     = (const float*)d_in[13];

    ushort* aob = (ushort*)d_ws;                    // [NPIX][192] bf16
    ushort* qb  = aob + (size_t)NPIX_ * C_;         // [NPIX][192] bf16
    ushort* kvb = qb  + (size_t)NPIX_ * C_;         // [NPIX][12][K16|V16] bf16
    ushort* Wt  = kvb + (size_t)NPIX_ * 2 * C_;     // transposed bf16 weights
    ushort* W1T = Wt + 110592;
    ushort* W2T = Wt + 184320;

    prep_kernel<<<1008, 256, 0, stream>>>(Wq, Wk, Wv, W1, W2, Wt);

    proj_kernel<<<1296, 256, 0, stream>>>(q, k, v, Wt, bq, bk, bv, qb, kvb);

    deform_attn_kernel<<<NPIX_ * G_ / 64, 256, 0, stream>>>(qb, kvb, offset, aob);

    mlp_fused_kernel<<<NPIX_ / 64, 256, 0, stream>>>(
        aob, W1T, W2T, b1, b2, (float*)d_out);
}